// Round 9
// baseline (194.751 us; speedup 1.0000x reference)
//
#include <hip/hip_runtime.h>

#define Bq 4
#define Cc 2048
#define Ss 1024
#define Hh 16
#define Dd 128

// 1/sqrt(128) * log2(e): softmax runs in exp2 domain, folded into Q at prep
#define QSCALE 0.127517429f

typedef __bf16 bf16x8 __attribute__((ext_vector_type(8)));
typedef float  f32x4  __attribute__((ext_vector_type(4)));

__device__ __forceinline__ ushort f2bf(float f) {
    uint u = __float_as_uint(f);
    u += 0x7FFFu + ((u >> 16) & 1u);   // RNE
    return (ushort)(u >> 16);
}
__device__ __forceinline__ uint pack2bf(float a, float b) {
    return (uint)f2bf(a) | ((uint)f2bf(b) << 16);
}
__device__ __forceinline__ void gld16(const void* g, void* l) {
    __builtin_amdgcn_global_load_lds(
        (const __attribute__((address_space(1))) unsigned int*)g,
        (__attribute__((address_space(3))) unsigned int*)l, 16, 0, 0);
}

// ---------------------------------------------------------------------------
// prep_all2: one kernel, five block-ranges (256 thr each).
//   [0,2048)     W fp32[2048][2048] -> bf16, intra-128B XOR swizzle (row&7)
//   [2048,6144)  V fp32 -> bf16, k-permuted (swapped-QK P layout) + swizzle
//   [6144,7168)  K transpose [d][S] -> [S][128] bf16, XOR swizzle by k&7
//   [7168,8192)  Q transpose [d][S] -> [S][128] bf16, scaled, no swizzle
//   [8192]       mask -> bias (0/-1e30), runtime dtype detection
// ---------------------------------------------------------------------------
__global__ __launch_bounds__(256) void prep_all2(const float* __restrict__ w,
                                                 const float* __restrict__ v,
                                                 const float* __restrict__ keys,
                                                 const float* __restrict__ queries,
                                                 const unsigned* __restrict__ mask,
                                                 ushort* __restrict__ wb,
                                                 ushort* __restrict__ vb,
                                                 ushort* __restrict__ Kt,
                                                 ushort* __restrict__ Qt,
                                                 float* __restrict__ bias) {
    __shared__ __align__(16) float T[128][65];
    const int t = threadIdx.x;
    const int blk = blockIdx.x;

    if (blk < 2048) {
        // ---- W convert+swizzle ----
        const size_t e = ((size_t)blk * 256 + t) * 8;
        const int row = (int)(e >> 11), col = (int)(e & 2047);
        const int colS = (col & ~63) | ((col & 63) ^ ((row & 7) << 3));
        float4 v0 = *(const float4*)&w[e];
        float4 v1 = *(const float4*)&w[e + 4];
        uint4 o;
        o.x = pack2bf(v0.x, v0.y); o.y = pack2bf(v0.z, v0.w);
        o.z = pack2bf(v1.x, v1.y); o.w = pack2bf(v1.z, v1.w);
        *(uint4*)&wb[(size_t)row * 2048 + colS] = o;
    } else if (blk < 6144) {
        // ---- V convert + k-permute + swizzle ----
        const int tid = (blk - 2048) * 256 + t;    // 0 .. 1M-1
        const int row = tid >> 7;                   // 0..8191
        const int cp = tid & 127;
        const int blk64 = (cp >> 3) * 64;
        const int j0 = cp & 7;
        const int b5 = j0 >> 2, h = j0 & 3;
        const float* src = v + (size_t)row * 1024 + blk64 + 32 * b5 + 4 * h;
        float4 A = *(const float4*)src;
        float4 B = *(const float4*)(src + 16);
        uint4 o;
        o.x = pack2bf(A.x, A.y); o.y = pack2bf(A.z, A.w);
        o.z = pack2bf(B.x, B.y); o.w = pack2bf(B.z, B.w);
        *(uint4*)&vb[(size_t)row * 1024 + blk64 + ((j0 * 8) ^ ((row & 7) << 3))] = o;
    } else if (blk < 8192) {
        // ---- K or Q transpose+convert (+swizzle for K, +scale for Q) ----
        const int isQ = (blk >= 7168);
        const int b2 = blk - (isQ ? 7168 : 6144);
        const int s0 = (b2 & 15) * 64;
        const int bh = b2 >> 4;
        const float* src = (isQ ? queries : keys) + (size_t)bh * 128 * 1024;
        const float sc = isQ ? QSCALE : 1.0f;
#pragma unroll
        for (int p = 0; p < 8; ++p) {
            const int d = p * 16 + (t >> 4);
            float4 v4 = *(const float4*)&src[(size_t)d * 1024 + s0 + (t & 15) * 4];
            T[d][(t & 15) * 4 + 0] = v4.x * sc;
            T[d][(t & 15) * 4 + 1] = v4.y * sc;
            T[d][(t & 15) * 4 + 2] = v4.z * sc;
            T[d][(t & 15) * 4 + 3] = v4.w * sc;
        }
        __syncthreads();
        ushort* outp = isQ ? Qt : Kt;
#pragma unroll
        for (int p = 0; p < 4; ++p) {
            const int k = p * 16 + (t >> 4);
            const int x = t & 15;
            uint4 o;
            o.x = pack2bf(T[x * 8 + 0][k], T[x * 8 + 1][k]);
            o.y = pack2bf(T[x * 8 + 2][k], T[x * 8 + 3][k]);
            o.z = pack2bf(T[x * 8 + 4][k], T[x * 8 + 5][k]);
            o.w = pack2bf(T[x * 8 + 6][k], T[x * 8 + 7][k]);
            const size_t rowbyte = ((size_t)bh * 1024 + s0 + k) * 256;
            const int boff = isQ ? (x * 16) : ((x * 16) ^ ((k & 7) << 4));
            *(uint4*)((char*)outp + rowbyte + boff) = o;
        }
    } else {
        // ---- mask -> bias ----
        __shared__ int f01, ff;
        if (t == 0) { f01 = 0; ff = 0; }
        __syncthreads();
        int a = 0, c = 0;
        for (int i = t; i < 1024; i += 256) {
            unsigned vv = mask[i];
            if (vv != 0u && vv != 1u) a = 1;
            if (vv != 0u && vv != 0x3F800000u) c = 1;
        }
        if (a) atomicOr(&f01, 1);
        if (c) atomicOr(&ff, 1);
        __syncthreads();
        const int mode = f01 ? (ff ? 1 : 2) : 0;
        const int* mi = (const int*)mask;
        const unsigned char* mb = (const unsigned char*)mask;
        const float* mf = (const float*)mask;
        for (int i = t; i < Bq * Ss; i += 256) {
            bool on;
            if (mode == 0)      on = (mi[i] != 0);
            else if (mode == 1) on = (mb[i] != 0);
            else                on = (mf[i] != 0.0f);
            bias[i] = on ? 0.0f : -1e30f;
        }
    }
}

// ---------------------------------------------------------------------------
// MFMA flash attention v8. 256 blocks x 512 thr (8 waves); q-tile 256;
// KVBLK 64 DOUBLE-buffered (68 KB LDS -> 2 blocks/CU = 4 waves/SIMD, so
// LDS/MFMA/VALU pipes overlap across blocks). Swapped-QK, P in registers,
// bias as MFMA C-init, stage->compute->drain->barrier per chunk.
// ---------------------------------------------------------------------------
__global__ __launch_bounds__(512, 4) void attn8(const ushort* __restrict__ Qt,
                                                const ushort* __restrict__ Kt,
                                                const ushort* __restrict__ Vbf,
                                                const float* __restrict__ bias,
                                                ushort* __restrict__ hidT) {
    __shared__ __align__(16) char SMEM[69632];
    // K: 2 x [64][128] (16 KB) at 0; V: 2 x [128][64] at 32768; bias at 65536
    float* biasS = (float*)(SMEM + 65536);

    const int t = threadIdx.x, l = t & 63, w = t >> 6;   // w = 0..7
    const int kk = l & 15, g = l >> 4;

    const int bid = blockIdx.x;
    const int vid = (bid & 7) * 32 + (bid >> 3);   // XCD-affine (256 blocks)
    const int bh = vid >> 2, qt = vid & 3;
    const int b = bh >> 4, hh = bh & 15;
    const int q0 = qt * 256;
    const size_t bhbase = (size_t)bh * 1024;

    for (int i = t; i < Ss; i += 512) biasS[i] = bias[b * Ss + i];

    // Q fragments (B-operand) from prepped Qt
    bf16x8 qf[2][4];
#pragma unroll
    for (int qs = 0; qs < 2; ++qs) {
        const ushort* qrow = Qt + (bhbase + q0 + w * 32 + qs * 16 + kk) * 128;
#pragma unroll
        for (int dc = 0; dc < 4; ++dc)
            qf[qs][dc] = *(const bf16x8*)(qrow + dc * 32 + g * 8);
    }

    float lrun[2] = {0.0f, 0.0f};
    f32x4 hacc[2][8];
#pragma unroll
    for (int qs = 0; qs < 2; ++qs)
#pragma unroll
        for (int i = 0; i < 8; ++i) hacc[qs][i] = (f32x4){0.f, 0.f, 0.f, 0.f};

#define ATTN_STAGE(bufi, cki)                                                   \
    {                                                                           \
        const int k0n = (cki) * 64;                                             \
        ushort* Kd = (ushort*)SMEM + (bufi) * 8192;                             \
        ushort* Vd = (ushort*)(SMEM + 32768) + (bufi) * 8192;                   \
        _Pragma("unroll")                                                       \
        for (int ii = 0; ii < 4; ++ii) {                                        \
            const int inst = ii * 8 + w;                                        \
            if (inst < 16) {                                                    \
                gld16(Kt + (bhbase + k0n + inst * 4 + (l >> 4)) * 128 +         \
                          (l & 15) * 8,                                         \
                      Kd + inst * 512);                                         \
            } else {                                                            \
                const int i2 = inst - 16;                                       \
                gld16(Vbf + ((size_t)bh * 128 + i2 * 8 + (l >> 3)) * 1024 +     \
                          k0n + (l & 7) * 8,                                    \
                      Vd + i2 * 512);                                           \
            }                                                                   \
        }                                                                       \
    }

#define ATTN_COMPUTE(bi, ck)                                                     \
    {                                                                            \
        const int k0 = (ck) * 64;                                                \
        const ushort* KTb = (const ushort*)SMEM + (bi) * 8192;                   \
        const ushort* Vsb = (const ushort*)(SMEM + 32768) + (bi) * 8192;         \
        f32x4 sc[2][4];                                                          \
        __builtin_amdgcn_s_setprio(1);                                           \
        _Pragma("unroll")                                                        \
        for (int ns = 0; ns < 4; ++ns) {                                         \
            const f32x4 ci = *(const f32x4*)&biasS[k0 + ns * 16 + g * 4];        \
            bf16x8 kf[4];                                                        \
            const ushort* kr = KTb + (ns * 16 + kk) * 128;                       \
            _Pragma("unroll")                                                    \
            for (int dc = 0; dc < 4; ++dc)                                       \
                kf[dc] = *(const bf16x8*)(kr +                                   \
                             ((dc * 32 + g * 8) ^ ((kk & 7) << 3)));             \
            _Pragma("unroll")                                                    \
            for (int qs = 0; qs < 2; ++qs) {                                     \
                f32x4 a = ci;                                                    \
                _Pragma("unroll")                                                \
                for (int dc = 0; dc < 4; ++dc)                                   \
                    a = __builtin_amdgcn_mfma_f32_16x16x32_bf16(                 \
                        kf[dc], qf[qs][dc], a, 0, 0, 0);                         \
                sc[qs][ns] = a;                                                  \
            }                                                                    \
        }                                                                        \
        __builtin_amdgcn_s_setprio(0);                                           \
        bf16x8 pb[2][2];                                                         \
        _Pragma("unroll")                                                        \
        for (int qs = 0; qs < 2; ++qs) {                                         \
            float pv[4][4];                                                      \
            float s = 0.0f;                                                      \
            _Pragma("unroll")                                                    \
            for (int ns = 0; ns < 4; ++ns) {                                     \
                _Pragma("unroll")                                                \
                for (int r = 0; r < 4; ++r) {                                    \
                    float p = exp2f(sc[qs][ns][r]);                              \
                    pv[ns][r] = p;                                               \
                    s += p;                                                      \
                }                                                                \
            }                                                                    \
            lrun[qs] += s;                                                       \
            _Pragma("unroll")                                                    \
            for (int kh = 0; kh < 2; ++kh) {                                     \
                bf16x8 vpk;                                                      \
                _Pragma("unroll")                                                \
                for (int j = 0; j < 8; ++j)                                      \
                    vpk[j] = (__bf16)pv[2 * kh + (j >> 2)][j & 3];               \
                pb[qs][kh] = vpk;                                                \
            }                                                                    \
        }                                                                        \
        __builtin_amdgcn_s_setprio(1);                                           \
        _Pragma("unroll")                                                        \
        for (int kh = 0; kh < 2; ++kh) {                                         \
            _Pragma("unroll")                                                    \
            for (int ds = 0; ds < 8; ++ds) {                                     \
                bf16x8 vf = *(const bf16x8*)(Vsb + (ds * 16 + kk) * 64 +         \
                                 ((kh * 32 + g * 8) ^ ((kk & 7) << 3)));         \
                hacc[0][ds] = __builtin_amdgcn_mfma_f32_16x16x32_bf16(           \
                    vf, pb[0][kh], hacc[0][ds], 0, 0, 0);                        \
                hacc[1][ds] = __builtin_amdgcn_mfma_f32_16x16x32_bf16(           \
                    vf, pb[1][kh], hacc[1][ds], 0, 0, 0);                        \
            }                                                                    \
        }                                                                        \
        __builtin_amdgcn_s_setprio(0);                                           \
    }

    // prologue: stage chunk 0, drain, barrier
    ATTN_STAGE(0, 0);
    asm volatile("s_waitcnt vmcnt(0)" ::: "memory");
    __builtin_amdgcn_s_barrier();

    int buf = 0;
    for (int ck = 0; ck < 16; ++ck) {
        if (ck + 1 < 16) ATTN_STAGE(buf ^ 1, ck + 1);  // issue next chunk
        ATTN_COMPUTE(buf, ck);                          // hides the loads
        asm volatile("s_waitcnt vmcnt(0)" ::: "memory"); // next chunk landed
        __builtin_amdgcn_s_barrier();
        buf ^= 1;
    }
#undef ATTN_STAGE
#undef ATTN_COMPUTE

    float linv[2];
#pragma unroll
    for (int qs = 0; qs < 2; ++qs) {
        float s = lrun[qs];
        s += __shfl_xor(s, 16);
        s += __shfl_xor(s, 32);
        linv[qs] = 1.0f / s;
    }

    __syncthreads();   // done with K/V buffers; reuse as [256 q][128 d] stage
    {
        ushort* hs = (ushort*)SMEM;
#pragma unroll
        for (int qs = 0; qs < 2; ++qs) {
            const int row = w * 32 + qs * 16 + kk;
#pragma unroll
            for (int ds = 0; ds < 8; ++ds) {
                uint2 pk;
                pk.x = pack2bf(hacc[qs][ds][0] * linv[qs], hacc[qs][ds][1] * linv[qs]);
                pk.y = pack2bf(hacc[qs][ds][2] * linv[qs], hacc[qs][ds][3] * linv[qs]);
                const int off = row * 256 + ((ds * 32 + g * 8) ^ ((row & 7) << 4));
                *(uint2*)((char*)hs + off) = pk;
            }
        }
    }
    __syncthreads();

    const char* hsb = (const char*)SMEM;
#pragma unroll
    for (int it = 0; it < 8; ++it) {
        const int idx = it * 512 + t;                  // 0..4095
        const int q = idx >> 4, x = idx & 15;
        uint4 vv = *(const uint4*)(hsb + q * 256 + x * 16);
        *(uint4*)((char*)hidT + ((size_t)(b * Ss + q0 + q)) * 4096 + hh * 256 + x * 16) = vv;
    }
}

// ---------------------------------------------------------------------------
// proj5: out[2048][4096] = W @ hidT^T. BM=128, BN=256, BK=64, 512 thr
// (8 waves 2Mx4N, per-wave 64x64). 2 phases per K-tile, 16 MFMA/phase,
// ds_read ∥ stage-issue ∥ MFMA per phase, 3-buffer LDS, vmcnt(6)/K-tile.
// ---------------------------------------------------------------------------
__global__ __launch_bounds__(512, 2) void proj5(const ushort* __restrict__ Wbf,
                                                const ushort* __restrict__ hidT,
                                                float* __restrict__ out) {
    __shared__ __align__(16) char SMEM[147456];
    const int t = threadIdx.x, l = t & 63, w = t >> 6;
    const int kk = l & 15, g = l >> 4;
    const int wr = w >> 2, wc = w & 3;

    const int bid = blockIdx.x;
    const int vid = (bid & 7) * 32 + (bid >> 3);   // 256 blocks, XCD-bijective
    const int o0 = (vid & 15) * 128;               // 16 M-tiles
    const int n0 = (vid >> 4) * 256;               // 16 N-tiles

    f32x4 acc[4][4];
#pragma unroll
    for (int i = 0; i < 4; ++i)
#pragma unroll
        for (int j = 0; j < 4; ++j) acc[i][j] = (f32x4){0.f, 0.f, 0.f, 0.f};

    const int swz = (kk & 7) << 3;

#define P5_STAGE_A(st, ks)                                                      \
    {                                                                           \
        ushort* Ad = (ushort*)SMEM + (st) * 8192;                               \
        _Pragma("unroll")                                                       \
        for (int ii = 0; ii < 2; ++ii) {                                        \
            const int idx = ii * 512 + t;                                       \
            gld16(Wbf + (size_t)(o0 + (idx >> 3)) * 2048 + (ks) * 64 +          \
                      (idx & 7) * 8,                                            \
                  Ad + idx * 8);                                                \
        }                                                                       \
    }
#define P5_STAGE_B(st, ks, p)                                                   \
    {                                                                           \
        ushort* Bd = (ushort*)(SMEM + 49152) + (st) * 16384;                    \
        _Pragma("unroll")                                                       \
        for (int jj = (p) * 2; jj < (p) * 2 + 2; ++jj) {                        \
            const int idx = jj * 512 + t;                                       \
            gld16(hidT + (size_t)(n0 + (idx >> 3)) * 2048 + (ks) * 64 +         \
                      (idx & 7) * 8,                                            \
                  Bd + idx * 8);                                                \
        }                                                                       \
    }
#define P5_READ(dcv)                                                            \
    _Pragma("unroll")                                                           \
    for (int ms = 0; ms < 4; ++ms)                                              \
        af[ms] = *(const bf16x8*)&Ab[(wr * 64 + ms * 16 + kk) * 64 +            \
                                     (((dcv) * 32 + g * 8) ^ swz)];             \
    _Pragma("unroll")                                                           \
    for (int ns = 0; ns < 4; ++ns)                                              \
        bfr[ns] = *(const bf16x8*)&Bb[(wc * 64 + ns * 16 + kk) * 64 +           \
                                      (((dcv) * 32 + g * 8) ^ swz)];
#define P5_MFMA()                                                               \
    __builtin_amdgcn_s_setprio(1);                                              \
    _Pragma("unroll")                                                           \
    for (int ms = 0; ms < 4; ++ms)                                              \
        _Pragma("unroll")                                                       \
        for (int ns = 0; ns < 4; ++ns)                                          \
            acc[ms][ns] = __builtin_amdgcn_mfma_f32_16x16x32_bf16(              \
                af[ms], bfr[ns], acc[ms][ns], 0, 0, 0);                         \
    __builtin_amdgcn_s_setprio(0);

    P5_STAGE_A(0, 0); P5_STAGE_B(0, 0, 0); P5_STAGE_B(0, 0, 1);
    P5_STAGE_A(1, 1); P5_STAGE_B(1, 1, 0); P5_STAGE_B(1, 1, 1);
    asm volatile("s_waitcnt vmcnt(6)" ::: "memory");
    __builtin_amdgcn_s_barrier();

    int ct = 0, st2 = 2;
    for (int tt = 0; tt < 32; ++tt) {
        const ushort* Ab = (const ushort*)SMEM + ct * 8192;
        const ushort* Bb = (const ushort*)(SMEM + 49152) + ct * 16384;
        bf16x8 af[4], bfr[4];

        // ---- phase 0 (dc=0): ds_read 8 ∥ stage A + B-half ----
        P5_READ(0);
        if (tt < 30) { P5_STAGE_A(st2, tt + 2); P5_STAGE_B(st2, tt + 2, 0); }
        __builtin_amdgcn_s_barrier();
        asm volatile("s_waitcnt lgkmcnt(0)" ::: "memory");
        P5_MFMA();
        __builtin_amdgcn_s_barrier();

        // ---- phase 1 (dc=1): ds_read 8 ∥ stage B-half; counted vmcnt ----
        P5_READ(1);
        if (tt < 30) P5_STAGE_B(st2, tt + 2, 1);
        if (tt < 30) { asm volatile("s_waitcnt vmcnt(6)" ::: "memory"); }
        else         { asm volatile("s_waitcnt vmcnt(0)" ::: "memory"); }
        __builtin_amdgcn_s_barrier();
        asm volatile("s_waitcnt lgkmcnt(0)" ::: "memory");
        P5_MFMA();
        __builtin_amdgcn_s_barrier();

        ct = (ct == 2) ? 0 : ct + 1;
        st2 = (st2 == 2) ? 0 : st2 + 1;
    }
#undef P5_STAGE_A
#undef P5_STAGE_B
#undef P5_READ
#undef P5_MFMA

#pragma unroll
    for (int ms = 0; ms < 4; ++ms)
#pragma unroll
        for (int ns = 0; ns < 4; ++ns) {
            const int o = o0 + wr * 64 + ms * 16 + g * 4;
            const int n = n0 + wc * 64 + ns * 16 + kk;
            const int bb = n >> 10, qq = n & 1023;
            float* op = out + ((size_t)(bb * Cc + o)) * Ss + qq;
#pragma unroll
            for (int r = 0; r < 4; ++r) op[(size_t)r * Ss] = acc[ms][ns][r];
        }
}

extern "C" void kernel_launch(void* const* d_in, const int* in_sizes, int n_in,
                              void* d_out, int out_size, void* d_ws, size_t ws_size,
                              hipStream_t stream) {
    const float*    keys    = (const float*)d_in[0];
    const float*    values  = (const float*)d_in[1];
    const float*    queries = (const float*)d_in[2];
    const unsigned* mask    = (const unsigned*)d_in[3];
    const float*    w_out   = (const float*)d_in[4];
    float* out = (float*)d_out;

    char* ws = (char*)d_ws;
    float*  bias = (float*)ws;                              // 16 KB
    ushort* Wbf  = (ushort*)(ws + 16384);                   // 8 MB
    ushort* Kt   = (ushort*)(ws + 16384 + (8u << 20));      // 16 MB
    ushort* Qt   = (ushort*)(ws + 16384 + (24u << 20));     // 16 MB
    ushort* Vbf  = (ushort*)(ws + 16384 + (40u << 20));     // 16 MB
    ushort* hidT = (ushort*)(ws + 16384 + (56u << 20));     // 16 MB

    hipLaunchKernelGGL(prep_all2, dim3(8193), dim3(256), 0, stream,
                       w_out, values, keys, queries, mask,
                       Wbf, Vbf, Kt, Qt, bias);
    hipLaunchKernelGGL(attn8, dim3(256), dim3(512), 0, stream,
                       Qt, Kt, Vbf, bias, hidT);
    hipLaunchKernelGGL(proj5, dim3(256), dim3(512), 0, stream,
                       Wbf, hidT, out);
}

// Round 10
// 120.859 us; speedup vs baseline: 1.6114x; 1.6114x over previous
//
#include <hip/hip_runtime.h>

#define Bq 4
#define Cc 2048
#define Ss 1024
#define Hh 16
#define Dd 128

// 1/sqrt(128) * log2(e): softmax runs in exp2 domain, folded into Q at prep
#define QSCALE 0.127517429f

typedef __bf16 bf16x8 __attribute__((ext_vector_type(8)));
typedef float  f32x4  __attribute__((ext_vector_type(4)));

__device__ __forceinline__ ushort f2bf(float f) {
    uint u = __float_as_uint(f);
    u += 0x7FFFu + ((u >> 16) & 1u);   // RNE
    return (ushort)(u >> 16);
}
__device__ __forceinline__ uint pack2bf(float a, float b) {
    return (uint)f2bf(a) | ((uint)f2bf(b) << 16);
}
__device__ __forceinline__ void gld16(const void* g, void* l) {
    __builtin_amdgcn_global_load_lds(
        (const __attribute__((address_space(1))) unsigned int*)g,
        (__attribute__((address_space(3))) unsigned int*)l, 16, 0, 0);
}

// ---------------------------------------------------------------------------
// prep_all2: one kernel, five block-ranges (256 thr each).
//   [0,2048)     W fp32[2048][2048] -> bf16, intra-128B XOR swizzle (row&7)
//   [2048,6144)  V fp32 -> bf16, k-permuted (swapped-QK P layout) + swizzle
//   [6144,7168)  K transpose [d][S] -> [S][128] bf16, XOR swizzle by k&7
//   [7168,8192)  Q transpose [d][S] -> [S][128] bf16, scaled, no swizzle
//   [8192]       mask -> bias (0/-1e30), runtime dtype detection
// ---------------------------------------------------------------------------
__global__ __launch_bounds__(256) void prep_all2(const float* __restrict__ w,
                                                 const float* __restrict__ v,
                                                 const float* __restrict__ keys,
                                                 const float* __restrict__ queries,
                                                 const unsigned* __restrict__ mask,
                                                 ushort* __restrict__ wb,
                                                 ushort* __restrict__ vb,
                                                 ushort* __restrict__ Kt,
                                                 ushort* __restrict__ Qt,
                                                 float* __restrict__ bias) {
    __shared__ __align__(16) float T[128][65];
    const int t = threadIdx.x;
    const int blk = blockIdx.x;

    if (blk < 2048) {
        // ---- W convert+swizzle ----
        const size_t e = ((size_t)blk * 256 + t) * 8;
        const int row = (int)(e >> 11), col = (int)(e & 2047);
        const int colS = (col & ~63) | ((col & 63) ^ ((row & 7) << 3));
        float4 v0 = *(const float4*)&w[e];
        float4 v1 = *(const float4*)&w[e + 4];
        uint4 o;
        o.x = pack2bf(v0.x, v0.y); o.y = pack2bf(v0.z, v0.w);
        o.z = pack2bf(v1.x, v1.y); o.w = pack2bf(v1.z, v1.w);
        *(uint4*)&wb[(size_t)row * 2048 + colS] = o;
    } else if (blk < 6144) {
        // ---- V convert + k-permute + swizzle ----
        const int tid = (blk - 2048) * 256 + t;    // 0 .. 1M-1
        const int row = tid >> 7;                   // 0..8191
        const int cp = tid & 127;
        const int blk64 = (cp >> 3) * 64;
        const int j0 = cp & 7;
        const int b5 = j0 >> 2, h = j0 & 3;
        const float* src = v + (size_t)row * 1024 + blk64 + 32 * b5 + 4 * h;
        float4 A = *(const float4*)src;
        float4 B = *(const float4*)(src + 16);
        uint4 o;
        o.x = pack2bf(A.x, A.y); o.y = pack2bf(A.z, A.w);
        o.z = pack2bf(B.x, B.y); o.w = pack2bf(B.z, B.w);
        *(uint4*)&vb[(size_t)row * 1024 + blk64 + ((j0 * 8) ^ ((row & 7) << 3))] = o;
    } else if (blk < 8192) {
        // ---- K or Q transpose+convert (+swizzle for K, +scale for Q) ----
        const int isQ = (blk >= 7168);
        const int b2 = blk - (isQ ? 7168 : 6144);
        const int s0 = (b2 & 15) * 64;
        const int bh = b2 >> 4;
        const float* src = (isQ ? queries : keys) + (size_t)bh * 128 * 1024;
        const float sc = isQ ? QSCALE : 1.0f;
#pragma unroll
        for (int p = 0; p < 8; ++p) {
            const int d = p * 16 + (t >> 4);
            float4 v4 = *(const float4*)&src[(size_t)d * 1024 + s0 + (t & 15) * 4];
            T[d][(t & 15) * 4 + 0] = v4.x * sc;
            T[d][(t & 15) * 4 + 1] = v4.y * sc;
            T[d][(t & 15) * 4 + 2] = v4.z * sc;
            T[d][(t & 15) * 4 + 3] = v4.w * sc;
        }
        __syncthreads();
        ushort* outp = isQ ? Qt : Kt;
#pragma unroll
        for (int p = 0; p < 4; ++p) {
            const int k = p * 16 + (t >> 4);
            const int x = t & 15;
            uint4 o;
            o.x = pack2bf(T[x * 8 + 0][k], T[x * 8 + 1][k]);
            o.y = pack2bf(T[x * 8 + 2][k], T[x * 8 + 3][k]);
            o.z = pack2bf(T[x * 8 + 4][k], T[x * 8 + 5][k]);
            o.w = pack2bf(T[x * 8 + 6][k], T[x * 8 + 7][k]);
            const size_t rowbyte = ((size_t)bh * 1024 + s0 + k) * 256;
            const int boff = isQ ? (x * 16) : ((x * 16) ^ ((k & 7) << 4));
            *(uint4*)((char*)outp + rowbyte + boff) = o;
        }
    } else {
        // ---- mask -> bias ----
        __shared__ int f01, ff;
        if (t == 0) { f01 = 0; ff = 0; }
        __syncthreads();
        int a = 0, c = 0;
        for (int i = t; i < 1024; i += 256) {
            unsigned vv = mask[i];
            if (vv != 0u && vv != 1u) a = 1;
            if (vv != 0u && vv != 0x3F800000u) c = 1;
        }
        if (a) atomicOr(&f01, 1);
        if (c) atomicOr(&ff, 1);
        __syncthreads();
        const int mode = f01 ? (ff ? 1 : 2) : 0;
        const int* mi = (const int*)mask;
        const unsigned char* mb = (const unsigned char*)mask;
        const float* mf = (const float*)mask;
        for (int i = t; i < Bq * Ss; i += 256) {
            bool on;
            if (mode == 0)      on = (mi[i] != 0);
            else if (mode == 1) on = (mb[i] != 0);
            else                on = (mf[i] != 0.0f);
            bias[i] = on ? 0.0f : -1e30f;
        }
    }
}

// ---------------------------------------------------------------------------
// MFMA flash attention v9. 256 blocks x 512 thr (8 waves); q-tile 256;
// KVBLK 64 double-buffered; 68 KB LDS + VGPR<=128 (NO min-waves bound: the
// r9 lesson — __launch_bounds__(512,4) split the unified RF 64+64 and spilled)
// -> hardware gives 2 blocks/CU = 16 waves/CU; pipes overlap across blocks.
// Swapped-QK, P in registers, bias as MFMA C-init.
// ---------------------------------------------------------------------------
__global__ __launch_bounds__(512) void attn9(const ushort* __restrict__ Qt,
                                             const ushort* __restrict__ Kt,
                                             const ushort* __restrict__ Vbf,
                                             const float* __restrict__ bias,
                                             ushort* __restrict__ hidT) {
    __shared__ __align__(16) char SMEM[69632];
    // K: 2 x [64][128] (16 KB) at 0; V: 2 x [128][64] at 32768; bias at 65536
    float* biasS = (float*)(SMEM + 65536);

    const int t = threadIdx.x, l = t & 63, w = t >> 6;   // w = 0..7
    const int kk = l & 15, g = l >> 4;

    const int bid = blockIdx.x;
    const int vid = (bid & 7) * 32 + (bid >> 3);   // XCD-affine (256 blocks)
    const int bh = vid >> 2, qt = vid & 3;
    const int b = bh >> 4, hh = bh & 15;
    const int q0 = qt * 256;
    const size_t bhbase = (size_t)bh * 1024;

    for (int i = t; i < Ss; i += 512) biasS[i] = bias[b * Ss + i];

    // Q fragments (B-operand) from prepped Qt
    bf16x8 qf[2][4];
#pragma unroll
    for (int qs = 0; qs < 2; ++qs) {
        const ushort* qrow = Qt + (bhbase + q0 + w * 32 + qs * 16 + kk) * 128;
#pragma unroll
        for (int dc = 0; dc < 4; ++dc)
            qf[qs][dc] = *(const bf16x8*)(qrow + dc * 32 + g * 8);
    }

    float lrun[2] = {0.0f, 0.0f};
    f32x4 hacc[2][8];
#pragma unroll
    for (int qs = 0; qs < 2; ++qs)
#pragma unroll
        for (int i = 0; i < 8; ++i) hacc[qs][i] = (f32x4){0.f, 0.f, 0.f, 0.f};

#define ATTN_STAGE(bufi, cki)                                                   \
    {                                                                           \
        const int k0n = (cki) * 64;                                             \
        ushort* Kd = (ushort*)SMEM + (bufi) * 8192;                             \
        ushort* Vd = (ushort*)(SMEM + 32768) + (bufi) * 8192;                   \
        _Pragma("unroll")                                                       \
        for (int ii = 0; ii < 4; ++ii) {                                        \
            const int inst = ii * 8 + w;                                        \
            if (inst < 16) {                                                    \
                gld16(Kt + (bhbase + k0n + inst * 4 + (l >> 4)) * 128 +         \
                          (l & 15) * 8,                                         \
                      Kd + inst * 512);                                         \
            } else {                                                            \
                const int i2 = inst - 16;                                       \
                gld16(Vbf + ((size_t)bh * 128 + i2 * 8 + (l >> 3)) * 1024 +     \
                          k0n + (l & 7) * 8,                                    \
                      Vd + i2 * 512);                                           \
            }                                                                   \
        }                                                                       \
    }

#define ATTN_COMPUTE(bi, ck)                                                     \
    {                                                                            \
        const int k0 = (ck) * 64;                                                \
        const ushort* KTb = (const ushort*)SMEM + (bi) * 8192;                   \
        const ushort* Vsb = (const ushort*)(SMEM + 32768) + (bi) * 8192;         \
        f32x4 sc[2][4];                                                          \
        __builtin_amdgcn_s_setprio(1);                                           \
        _Pragma("unroll")                                                        \
        for (int ns = 0; ns < 4; ++ns) {                                         \
            const f32x4 ci = *(const f32x4*)&biasS[k0 + ns * 16 + g * 4];        \
            bf16x8 kf[4];                                                        \
            const ushort* kr = KTb + (ns * 16 + kk) * 128;                       \
            _Pragma("unroll")                                                    \
            for (int dc = 0; dc < 4; ++dc)                                       \
                kf[dc] = *(const bf16x8*)(kr +                                   \
                             ((dc * 32 + g * 8) ^ ((kk & 7) << 3)));             \
            _Pragma("unroll")                                                    \
            for (int qs = 0; qs < 2; ++qs) {                                     \
                f32x4 a = ci;                                                    \
                _Pragma("unroll")                                                \
                for (int dc = 0; dc < 4; ++dc)                                   \
                    a = __builtin_amdgcn_mfma_f32_16x16x32_bf16(                 \
                        kf[dc], qf[qs][dc], a, 0, 0, 0);                         \
                sc[qs][ns] = a;                                                  \
            }                                                                    \
        }                                                                        \
        __builtin_amdgcn_s_setprio(0);                                           \
        bf16x8 pb[2][2];                                                         \
        _Pragma("unroll")                                                        \
        for (int qs = 0; qs < 2; ++qs) {                                         \
            float pv[4][4];                                                      \
            float s = 0.0f;                                                      \
            _Pragma("unroll")                                                    \
            for (int ns = 0; ns < 4; ++ns) {                                     \
                _Pragma("unroll")                                                \
                for (int r = 0; r < 4; ++r) {                                    \
                    float p = exp2f(sc[qs][ns][r]);                              \
                    pv[ns][r] = p;                                               \
                    s += p;                                                      \
                }                                                                \
            }                                                                    \
            lrun[qs] += s;                                                       \
            _Pragma("unroll")                                                    \
            for (int kh = 0; kh < 2; ++kh) {                                     \
                bf16x8 vpk;                                                      \
                _Pragma("unroll")                                                \
                for (int j = 0; j < 8; ++j)                                      \
                    vpk[j] = (__bf16)pv[2 * kh + (j >> 2)][j & 3];               \
                pb[qs][kh] = vpk;                                                \
            }                                                                    \
        }                                                                        \
        __builtin_amdgcn_s_setprio(1);                                           \
        _Pragma("unroll")                                                        \
        for (int kh = 0; kh < 2; ++kh) {                                         \
            _Pragma("unroll")                                                    \
            for (int ds = 0; ds < 8; ++ds) {                                     \
                bf16x8 vf = *(const bf16x8*)(Vsb + (ds * 16 + kk) * 64 +         \
                                 ((kh * 32 + g * 8) ^ ((kk & 7) << 3)));         \
                hacc[0][ds] = __builtin_amdgcn_mfma_f32_16x16x32_bf16(           \
                    vf, pb[0][kh], hacc[0][ds], 0, 0, 0);                        \
                hacc[1][ds] = __builtin_amdgcn_mfma_f32_16x16x32_bf16(           \
                    vf, pb[1][kh], hacc[1][ds], 0, 0, 0);                        \
            }                                                                    \
        }                                                                        \
        __builtin_amdgcn_s_setprio(0);                                           \
    }

    // prologue: stage chunk 0, drain, barrier
    ATTN_STAGE(0, 0);
    asm volatile("s_waitcnt vmcnt(0)" ::: "memory");
    __builtin_amdgcn_s_barrier();

    int buf = 0;
    for (int ck = 0; ck < 16; ++ck) {
        if (ck + 1 < 16) ATTN_STAGE(buf ^ 1, ck + 1);  // issue next chunk
        ATTN_COMPUTE(buf, ck);                          // hides the loads
        asm volatile("s_waitcnt vmcnt(0)" ::: "memory"); // next chunk landed
        __builtin_amdgcn_s_barrier();
        buf ^= 1;
    }
#undef ATTN_STAGE
#undef ATTN_COMPUTE

    float linv[2];
#pragma unroll
    for (int qs = 0; qs < 2; ++qs) {
        float s = lrun[qs];
        s += __shfl_xor(s, 16);
        s += __shfl_xor(s, 32);
        linv[qs] = 1.0f / s;
    }

    __syncthreads();   // done with K/V buffers; reuse as [256 q][128 d] stage
    {
        ushort* hs = (ushort*)SMEM;
#pragma unroll
        for (int qs = 0; qs < 2; ++qs) {
            const int row = w * 32 + qs * 16 + kk;
#pragma unroll
            for (int ds = 0; ds < 8; ++ds) {
                uint2 pk;
                pk.x = pack2bf(hacc[qs][ds][0] * linv[qs], hacc[qs][ds][1] * linv[qs]);
                pk.y = pack2bf(hacc[qs][ds][2] * linv[qs], hacc[qs][ds][3] * linv[qs]);
                const int off = row * 256 + ((ds * 32 + g * 8) ^ ((row & 7) << 4));
                *(uint2*)((char*)hs + off) = pk;
            }
        }
    }
    __syncthreads();

    const char* hsb = (const char*)SMEM;
#pragma unroll
    for (int it = 0; it < 8; ++it) {
        const int idx = it * 512 + t;                  // 0..4095
        const int q = idx >> 4, x = idx & 15;
        uint4 vv = *(const uint4*)(hsb + q * 256 + x * 16);
        *(uint4*)((char*)hidT + ((size_t)(b * Ss + q0 + q)) * 4096 + hh * 256 + x * 16) = vv;
    }
}

// ---------------------------------------------------------------------------
// proj5: out[2048][4096] = W @ hidT^T. BM=128, BN=256, BK=64, 512 thr
// (8 waves 2Mx4N, per-wave 64x64). 2 phases per K-tile, 16 MFMA/phase,
// ds_read ∥ stage-issue ∥ MFMA per phase, 3-buffer LDS, vmcnt(6)/K-tile.
// ---------------------------------------------------------------------------
__global__ __launch_bounds__(512, 2) void proj5(const ushort* __restrict__ Wbf,
                                                const ushort* __restrict__ hidT,
                                                float* __restrict__ out) {
    __shared__ __align__(16) char SMEM[147456];
    const int t = threadIdx.x, l = t & 63, w = t >> 6;
    const int kk = l & 15, g = l >> 4;
    const int wr = w >> 2, wc = w & 3;

    const int bid = blockIdx.x;
    const int vid = (bid & 7) * 32 + (bid >> 3);   // 256 blocks, XCD-bijective
    const int o0 = (vid & 15) * 128;               // 16 M-tiles
    const int n0 = (vid >> 4) * 256;               // 16 N-tiles

    f32x4 acc[4][4];
#pragma unroll
    for (int i = 0; i < 4; ++i)
#pragma unroll
        for (int j = 0; j < 4; ++j) acc[i][j] = (f32x4){0.f, 0.f, 0.f, 0.f};

    const int swz = (kk & 7) << 3;

#define P5_STAGE_A(st, ks)                                                      \
    {                                                                           \
        ushort* Ad = (ushort*)SMEM + (st) * 8192;                               \
        _Pragma("unroll")                                                       \
        for (int ii = 0; ii < 2; ++ii) {                                        \
            const int idx = ii * 512 + t;                                       \
            gld16(Wbf + (size_t)(o0 + (idx >> 3)) * 2048 + (ks) * 64 +          \
                      (idx & 7) * 8,                                            \
                  Ad + idx * 8);                                                \
        }                                                                       \
    }
#define P5_STAGE_B(st, ks, p)                                                   \
    {                                                                           \
        ushort* Bd = (ushort*)(SMEM + 49152) + (st) * 16384;                    \
        _Pragma("unroll")                                                       \
        for (int jj = (p) * 2; jj < (p) * 2 + 2; ++jj) {                        \
            const int idx = jj * 512 + t;                                       \
            gld16(hidT + (size_t)(n0 + (idx >> 3)) * 2048 + (ks) * 64 +         \
                      (idx & 7) * 8,                                            \
                  Bd + idx * 8);                                                \
        }                                                                       \
    }
#define P5_READ(dcv)                                                            \
    _Pragma("unroll")                                                           \
    for (int ms = 0; ms < 4; ++ms)                                              \
        af[ms] = *(const bf16x8*)&Ab[(wr * 64 + ms * 16 + kk) * 64 +            \
                                     (((dcv) * 32 + g * 8) ^ swz)];             \
    _Pragma("unroll")                                                           \
    for (int ns = 0; ns < 4; ++ns)                                              \
        bfr[ns] = *(const bf16x8*)&Bb[(wc * 64 + ns * 16 + kk) * 64 +           \
                                      (((dcv) * 32 + g * 8) ^ swz)];
#define P5_MFMA()                                                               \
    __builtin_amdgcn_s_setprio(1);                                              \
    _Pragma("unroll")                                                           \
    for (int ms = 0; ms < 4; ++ms)                                              \
        _Pragma("unroll")                                                       \
        for (int ns = 0; ns < 4; ++ns)                                          \
            acc[ms][ns] = __builtin_amdgcn_mfma_f32_16x16x32_bf16(              \
                af[ms], bfr[ns], acc[ms][ns], 0, 0, 0);                         \
    __builtin_amdgcn_s_setprio(0);

    P5_STAGE_A(0, 0); P5_STAGE_B(0, 0, 0); P5_STAGE_B(0, 0, 1);
    P5_STAGE_A(1, 1); P5_STAGE_B(1, 1, 0); P5_STAGE_B(1, 1, 1);
    asm volatile("s_waitcnt vmcnt(6)" ::: "memory");
    __builtin_amdgcn_s_barrier();

    int ct = 0, st2 = 2;
    for (int tt = 0; tt < 32; ++tt) {
        const ushort* Ab = (const ushort*)SMEM + ct * 8192;
        const ushort* Bb = (const ushort*)(SMEM + 49152) + ct * 16384;
        bf16x8 af[4], bfr[4];

        // ---- phase 0 (dc=0): ds_read 8 ∥ stage A + B-half ----
        P5_READ(0);
        if (tt < 30) { P5_STAGE_A(st2, tt + 2); P5_STAGE_B(st2, tt + 2, 0); }
        __builtin_amdgcn_s_barrier();
        asm volatile("s_waitcnt lgkmcnt(0)" ::: "memory");
        P5_MFMA();
        __builtin_amdgcn_s_barrier();

        // ---- phase 1 (dc=1): ds_read 8 ∥ stage B-half; counted vmcnt ----
        P5_READ(1);
        if (tt < 30) P5_STAGE_B(st2, tt + 2, 1);
        if (tt < 30) { asm volatile("s_waitcnt vmcnt(6)" ::: "memory"); }
        else         { asm volatile("s_waitcnt vmcnt(0)" ::: "memory"); }
        __builtin_amdgcn_s_barrier();
        asm volatile("s_waitcnt lgkmcnt(0)" ::: "memory");
        P5_MFMA();
        __builtin_amdgcn_s_barrier();

        ct = (ct == 2) ? 0 : ct + 1;
        st2 = (st2 == 2) ? 0 : st2 + 1;
    }
#undef P5_STAGE_A
#undef P5_STAGE_B
#undef P5_READ
#undef P5_MFMA

#pragma unroll
    for (int ms = 0; ms < 4; ++ms)
#pragma unroll
        for (int ns = 0; ns < 4; ++ns) {
            const int o = o0 + wr * 64 + ms * 16 + g * 4;
            const int n = n0 + wc * 64 + ns * 16 + kk;
            const int bb = n >> 10, qq = n & 1023;
            float* op = out + ((size_t)(bb * Cc + o)) * Ss + qq;
#pragma unroll
            for (int r = 0; r < 4; ++r) op[(size_t)r * Ss] = acc[ms][ns][r];
        }
}

extern "C" void kernel_launch(void* const* d_in, const int* in_sizes, int n_in,
                              void* d_out, int out_size, void* d_ws, size_t ws_size,
                              hipStream_t stream) {
    const float*    keys    = (const float*)d_in[0];
    const float*    values  = (const float*)d_in[1];
    const float*    queries = (const float*)d_in[2];
    const unsigned* mask    = (const unsigned*)d_in[3];
    const float*    w_out   = (const float*)d_in[4];
    float* out = (float*)d_out;

    char* ws = (char*)d_ws;
    float*  bias = (float*)ws;                              // 16 KB
    ushort* Wbf  = (ushort*)(ws + 16384);                   // 8 MB
    ushort* Kt   = (ushort*)(ws + 16384 + (8u << 20));      // 16 MB
    ushort* Qt   = (ushort*)(ws + 16384 + (24u << 20));     // 16 MB
    ushort* Vbf  = (ushort*)(ws + 16384 + (40u << 20));     // 16 MB
    ushort* hidT = (ushort*)(ws + 16384 + (56u << 20));     // 16 MB

    hipLaunchKernelGGL(prep_all2, dim3(8193), dim3(256), 0, stream,
                       w_out, values, keys, queries, mask,
                       Wbf, Vbf, Kt, Qt, bias);
    hipLaunchKernelGGL(attn9, dim3(256), dim3(512), 0, stream,
                       Qt, Kt, Vbf, bias, hidT);
    hipLaunchKernelGGL(proj5, dim3(256), dim3(512), 0, stream,
                       Wbf, hidT, out);
}

// Round 11
// 119.028 us; speedup vs baseline: 1.6362x; 1.0154x over previous
//
#include <hip/hip_runtime.h>

#define Bq 4
#define Cc 2048
#define Ss 1024
#define Hh 16
#define Dd 128

// 1/sqrt(128) * log2(e): softmax runs in exp2 domain, folded into Q at prep
#define QSCALE 0.127517429f

typedef __bf16 bf16x8 __attribute__((ext_vector_type(8)));
typedef float  f32x4  __attribute__((ext_vector_type(4)));

__device__ __forceinline__ ushort f2bf(float f) {
    uint u = __float_as_uint(f);
    u += 0x7FFFu + ((u >> 16) & 1u);   // RNE
    return (ushort)(u >> 16);
}
__device__ __forceinline__ uint pack2bf(float a, float b) {
    return (uint)f2bf(a) | ((uint)f2bf(b) << 16);
}
__device__ __forceinline__ void gld16(const void* g, void* l) {
    __builtin_amdgcn_global_load_lds(
        (const __attribute__((address_space(1))) unsigned int*)g,
        (__attribute__((address_space(3))) unsigned int*)l, 16, 0, 0);
}

// ---------------------------------------------------------------------------
// prep_all2: one kernel, five block-ranges (256 thr each).
//   [0,2048)     W fp32[2048][2048] -> bf16, intra-128B XOR swizzle (row&7)
//   [2048,6144)  V fp32 -> bf16, k-permuted (swapped-QK P layout) + swizzle
//   [6144,7168)  K transpose [d][S] -> [S][128] bf16, XOR swizzle by k&7
//   [7168,8192)  Q transpose [d][S] -> [S][128] bf16, scaled, no swizzle
//   [8192]       mask -> bias (0/-1e30), runtime dtype detection
// ---------------------------------------------------------------------------
__global__ __launch_bounds__(256) void prep_all2(const float* __restrict__ w,
                                                 const float* __restrict__ v,
                                                 const float* __restrict__ keys,
                                                 const float* __restrict__ queries,
                                                 const unsigned* __restrict__ mask,
                                                 ushort* __restrict__ wb,
                                                 ushort* __restrict__ vb,
                                                 ushort* __restrict__ Kt,
                                                 ushort* __restrict__ Qt,
                                                 float* __restrict__ bias) {
    __shared__ __align__(16) float T[128][65];
    const int t = threadIdx.x;
    const int blk = blockIdx.x;

    if (blk < 2048) {
        // ---- W convert+swizzle ----
        const size_t e = ((size_t)blk * 256 + t) * 8;
        const int row = (int)(e >> 11), col = (int)(e & 2047);
        const int colS = (col & ~63) | ((col & 63) ^ ((row & 7) << 3));
        float4 v0 = *(const float4*)&w[e];
        float4 v1 = *(const float4*)&w[e + 4];
        uint4 o;
        o.x = pack2bf(v0.x, v0.y); o.y = pack2bf(v0.z, v0.w);
        o.z = pack2bf(v1.x, v1.y); o.w = pack2bf(v1.z, v1.w);
        *(uint4*)&wb[(size_t)row * 2048 + colS] = o;
    } else if (blk < 6144) {
        // ---- V convert + k-permute + swizzle ----
        const int tid = (blk - 2048) * 256 + t;    // 0 .. 1M-1
        const int row = tid >> 7;                   // 0..8191
        const int cp = tid & 127;
        const int blk64 = (cp >> 3) * 64;
        const int j0 = cp & 7;
        const int b5 = j0 >> 2, h = j0 & 3;
        const float* src = v + (size_t)row * 1024 + blk64 + 32 * b5 + 4 * h;
        float4 A = *(const float4*)src;
        float4 B = *(const float4*)(src + 16);
        uint4 o;
        o.x = pack2bf(A.x, A.y); o.y = pack2bf(A.z, A.w);
        o.z = pack2bf(B.x, B.y); o.w = pack2bf(B.z, B.w);
        *(uint4*)&vb[(size_t)row * 1024 + blk64 + ((j0 * 8) ^ ((row & 7) << 3))] = o;
    } else if (blk < 8192) {
        // ---- K or Q transpose+convert (+swizzle for K, +scale for Q) ----
        const int isQ = (blk >= 7168);
        const int b2 = blk - (isQ ? 7168 : 6144);
        const int s0 = (b2 & 15) * 64;
        const int bh = b2 >> 4;
        const float* src = (isQ ? queries : keys) + (size_t)bh * 128 * 1024;
        const float sc = isQ ? QSCALE : 1.0f;
#pragma unroll
        for (int p = 0; p < 8; ++p) {
            const int d = p * 16 + (t >> 4);
            float4 v4 = *(const float4*)&src[(size_t)d * 1024 + s0 + (t & 15) * 4];
            T[d][(t & 15) * 4 + 0] = v4.x * sc;
            T[d][(t & 15) * 4 + 1] = v4.y * sc;
            T[d][(t & 15) * 4 + 2] = v4.z * sc;
            T[d][(t & 15) * 4 + 3] = v4.w * sc;
        }
        __syncthreads();
        ushort* outp = isQ ? Qt : Kt;
#pragma unroll
        for (int p = 0; p < 4; ++p) {
            const int k = p * 16 + (t >> 4);
            const int x = t & 15;
            uint4 o;
            o.x = pack2bf(T[x * 8 + 0][k], T[x * 8 + 1][k]);
            o.y = pack2bf(T[x * 8 + 2][k], T[x * 8 + 3][k]);
            o.z = pack2bf(T[x * 8 + 4][k], T[x * 8 + 5][k]);
            o.w = pack2bf(T[x * 8 + 6][k], T[x * 8 + 7][k]);
            const size_t rowbyte = ((size_t)bh * 1024 + s0 + k) * 256;
            const int boff = isQ ? (x * 16) : ((x * 16) ^ ((k & 7) << 4));
            *(uint4*)((char*)outp + rowbyte + boff) = o;
        }
    } else {
        // ---- mask -> bias ----
        __shared__ int f01, ff;
        if (t == 0) { f01 = 0; ff = 0; }
        __syncthreads();
        int a = 0, c = 0;
        for (int i = t; i < 1024; i += 256) {
            unsigned vv = mask[i];
            if (vv != 0u && vv != 1u) a = 1;
            if (vv != 0u && vv != 0x3F800000u) c = 1;
        }
        if (a) atomicOr(&f01, 1);
        if (c) atomicOr(&ff, 1);
        __syncthreads();
        const int mode = f01 ? (ff ? 1 : 2) : 0;
        const int* mi = (const int*)mask;
        const unsigned char* mb = (const unsigned char*)mask;
        const float* mf = (const float*)mask;
        for (int i = t; i < Bq * Ss; i += 256) {
            bool on;
            if (mode == 0)      on = (mi[i] != 0);
            else if (mode == 1) on = (mb[i] != 0);
            else                on = (mf[i] != 0.0f);
            bias[i] = on ? 0.0f : -1e30f;
        }
    }
}

// ---------------------------------------------------------------------------
// MFMA flash attention v10. 256 blocks x 512 thr (8 waves); q-tile 256;
// KVBLK 64 TRIPLE-buffered, counted vmcnt(4). Swapped-QK, P in registers,
// bias as MFMA C-init. NEW: half-chunk issue-order pipeline —
//   QK(h0) -> QK(h1) -> SM(h0) -> PV(h0) -> SM(h1) -> PV(h1)
// so softmax VALU/trans issues while the other half's MFMAs drain the
// matrix pipe (in-order issue, independent registers => concurrent pipes).
// ---------------------------------------------------------------------------
__global__ __launch_bounds__(512) void attn10(const ushort* __restrict__ Qt,
                                              const ushort* __restrict__ Kt,
                                              const ushort* __restrict__ Vbf,
                                              const float* __restrict__ bias,
                                              ushort* __restrict__ hidT) {
    __shared__ __align__(16) char SMEM[102400];
    // K: 3 x [64][128] (16 KB) at 0; V: 3 x [128][64] at 49152; bias at 98304
    float* biasS = (float*)(SMEM + 98304);

    const int t = threadIdx.x, l = t & 63, w = t >> 6;   // w = 0..7
    const int kk = l & 15, g = l >> 4;

    const int bid = blockIdx.x;
    const int vid = (bid & 7) * 32 + (bid >> 3);   // XCD-affine (256 blocks)
    const int bh = vid >> 2, qt = vid & 3;
    const int b = bh >> 4, hh = bh & 15;
    const int q0 = qt * 256;
    const size_t bhbase = (size_t)bh * 1024;

    for (int i = t; i < Ss; i += 512) biasS[i] = bias[b * Ss + i];

    // Q fragments (B-operand) from prepped Qt
    bf16x8 qf[2][4];
#pragma unroll
    for (int qs = 0; qs < 2; ++qs) {
        const ushort* qrow = Qt + (bhbase + q0 + w * 32 + qs * 16 + kk) * 128;
#pragma unroll
        for (int dc = 0; dc < 4; ++dc)
            qf[qs][dc] = *(const bf16x8*)(qrow + dc * 32 + g * 8);
    }

    float lrun[2] = {0.0f, 0.0f};
    f32x4 hacc[2][8];
#pragma unroll
    for (int qs = 0; qs < 2; ++qs)
#pragma unroll
        for (int i = 0; i < 8; ++i) hacc[qs][i] = (f32x4){0.f, 0.f, 0.f, 0.f};

#define ATTN_STAGE(bufi, cki)                                                   \
    {                                                                           \
        const int k0n = (cki) * 64;                                             \
        ushort* Kd = (ushort*)SMEM + (bufi) * 8192;                             \
        ushort* Vd = (ushort*)(SMEM + 49152) + (bufi) * 8192;                   \
        _Pragma("unroll")                                                       \
        for (int ii = 0; ii < 4; ++ii) {                                        \
            const int inst = ii * 8 + w;                                        \
            if (inst < 16) {                                                    \
                gld16(Kt + (bhbase + k0n + inst * 4 + (l >> 4)) * 128 +         \
                          (l & 15) * 8,                                         \
                      Kd + inst * 512);                                         \
            } else {                                                            \
                const int i2 = inst - 16;                                       \
                gld16(Vbf + ((size_t)bh * 128 + i2 * 8 + (l >> 3)) * 1024 +     \
                          k0n + (l & 7) * 8,                                    \
                      Vd + i2 * 512);                                           \
            }                                                                   \
        }                                                                       \
    }

    // QK half h: ns = 2h, 2h+1 -> sc[qs][ns]
#define QK_HALF(h)                                                               \
    _Pragma("unroll")                                                            \
    for (int n2 = 0; n2 < 2; ++n2) {                                             \
        const int ns = 2 * (h) + n2;                                             \
        const f32x4 ci = *(const f32x4*)&biasS[k0 + ns * 16 + g * 4];            \
        bf16x8 kf[4];                                                            \
        const ushort* kr = KTb + (ns * 16 + kk) * 128;                           \
        _Pragma("unroll")                                                        \
        for (int dc = 0; dc < 4; ++dc)                                           \
            kf[dc] = *(const bf16x8*)(kr + ((dc * 32 + g * 8) ^ ((kk & 7) << 3)));\
        _Pragma("unroll")                                                        \
        for (int qs = 0; qs < 2; ++qs) {                                         \
            f32x4 a = ci;                                                        \
            _Pragma("unroll")                                                    \
            for (int dc = 0; dc < 4; ++dc)                                       \
                a = __builtin_amdgcn_mfma_f32_16x16x32_bf16(                     \
                    kf[dc], qf[qs][dc], a, 0, 0, 0);                             \
            sc[qs][ns] = a;                                                      \
        }                                                                        \
    }

    // SM half h: exp2 of sc[qs][2h],sc[qs][2h+1] -> pb[qs][h]; depends only
    // on QK half h, so its VALU/trans issues under the other half's MFMAs.
#define SM_HALF(h)                                                               \
    _Pragma("unroll")                                                            \
    for (int qs = 0; qs < 2; ++qs) {                                             \
        float pv0[4], pv1[4];                                                    \
        _Pragma("unroll")                                                        \
        for (int r = 0; r < 4; ++r) {                                            \
            pv0[r] = exp2f(sc[qs][2 * (h)][r]);                                  \
            pv1[r] = exp2f(sc[qs][2 * (h) + 1][r]);                              \
        }                                                                        \
        lrun[qs] += (pv0[0] + pv0[1] + pv0[2] + pv0[3])                          \
                  + (pv1[0] + pv1[1] + pv1[2] + pv1[3]);                         \
        bf16x8 vpk;                                                              \
        _Pragma("unroll")                                                        \
        for (int j = 0; j < 4; ++j) { vpk[j] = (__bf16)pv0[j];                   \
                                      vpk[j + 4] = (__bf16)pv1[j]; }             \
        pb[qs][h] = vpk;                                                         \
    }

#define PV_HALF(h)                                                               \
    _Pragma("unroll")                                                            \
    for (int ds = 0; ds < 8; ++ds) {                                             \
        bf16x8 vf = *(const bf16x8*)(Vsb + (ds * 16 + kk) * 64 +                 \
                        (((h) * 32 + g * 8) ^ ((kk & 7) << 3)));                 \
        hacc[0][ds] = __builtin_amdgcn_mfma_f32_16x16x32_bf16(                   \
            vf, pb[0][h], hacc[0][ds], 0, 0, 0);                                 \
        hacc[1][ds] = __builtin_amdgcn_mfma_f32_16x16x32_bf16(                   \
            vf, pb[1][h], hacc[1][ds], 0, 0, 0);                                 \
    }

#define ATTN_COMPUTE(bi, ck)                                                     \
    {                                                                            \
        const int k0 = (ck) * 64;                                                \
        const ushort* KTb = (const ushort*)SMEM + (bi) * 8192;                   \
        const ushort* Vsb = (const ushort*)(SMEM + 49152) + (bi) * 8192;         \
        f32x4 sc[2][4];                                                          \
        bf16x8 pb[2][2];                                                         \
        QK_HALF(0);                                                              \
        QK_HALF(1);                                                              \
        SM_HALF(0);   /* overlaps QK(1) matrix drain */                          \
        PV_HALF(0);                                                              \
        SM_HALF(1);   /* overlaps PV(0) matrix drain */                          \
        PV_HALF(1);                                                              \
    }

    // prologue: 2 tiles in flight; wait for tile 0 only (counted)
    ATTN_STAGE(0, 0);
    ATTN_STAGE(1, 1);
    asm volatile("s_waitcnt vmcnt(4)" ::: "memory");
    __builtin_amdgcn_s_barrier();

    int cb = 0, sb = 2;
    for (int ck = 0; ck < 14; ++ck) {
        ATTN_STAGE(sb, ck + 2);
        ATTN_COMPUTE(cb, ck);
        asm volatile("s_waitcnt vmcnt(4)" ::: "memory");  // next tile landed
        __builtin_amdgcn_s_barrier();
        cb = (cb == 2) ? 0 : cb + 1;
        sb = (sb == 2) ? 0 : sb + 1;
    }
    ATTN_COMPUTE(cb, 14);
    asm volatile("s_waitcnt vmcnt(0)" ::: "memory");
    __builtin_amdgcn_s_barrier();
    cb = (cb == 2) ? 0 : cb + 1;
    ATTN_COMPUTE(cb, 15);
#undef ATTN_STAGE
#undef ATTN_COMPUTE
#undef QK_HALF
#undef SM_HALF
#undef PV_HALF

    float linv[2];
#pragma unroll
    for (int qs = 0; qs < 2; ++qs) {
        float s = lrun[qs];
        s += __shfl_xor(s, 16);
        s += __shfl_xor(s, 32);
        linv[qs] = 1.0f / s;
    }

    __syncthreads();   // done with K/V buffers; reuse as [256 q][128 d] stage
    {
        ushort* hs = (ushort*)SMEM;
#pragma unroll
        for (int qs = 0; qs < 2; ++qs) {
            const int row = w * 32 + qs * 16 + kk;
#pragma unroll
            for (int ds = 0; ds < 8; ++ds) {
                uint2 pk;
                pk.x = pack2bf(hacc[qs][ds][0] * linv[qs], hacc[qs][ds][1] * linv[qs]);
                pk.y = pack2bf(hacc[qs][ds][2] * linv[qs], hacc[qs][ds][3] * linv[qs]);
                const int off = row * 256 + ((ds * 32 + g * 8) ^ ((row & 7) << 4));
                *(uint2*)((char*)hs + off) = pk;
            }
        }
    }
    __syncthreads();

    const char* hsb = (const char*)SMEM;
#pragma unroll
    for (int it = 0; it < 8; ++it) {
        const int idx = it * 512 + t;                  // 0..4095
        const int q = idx >> 4, x = idx & 15;
        uint4 vv = *(const uint4*)(hsb + q * 256 + x * 16);
        *(uint4*)((char*)hidT + ((size_t)(b * Ss + q0 + q)) * 4096 + hh * 256 + x * 16) = vv;
    }
}

// ---------------------------------------------------------------------------
// proj5: out[2048][4096] = W @ hidT^T. BM=128, BN=256, BK=64, 512 thr
// (8 waves 2Mx4N, per-wave 64x64). 2 phases per K-tile, 16 MFMA/phase,
// ds_read ∥ stage-issue ∥ MFMA per phase, 3-buffer LDS, vmcnt(6)/K-tile.
// ---------------------------------------------------------------------------
__global__ __launch_bounds__(512, 2) void proj5(const ushort* __restrict__ Wbf,
                                                const ushort* __restrict__ hidT,
                                                float* __restrict__ out) {
    __shared__ __align__(16) char SMEM[147456];
    const int t = threadIdx.x, l = t & 63, w = t >> 6;
    const int kk = l & 15, g = l >> 4;
    const int wr = w >> 2, wc = w & 3;

    const int bid = blockIdx.x;
    const int vid = (bid & 7) * 32 + (bid >> 3);   // 256 blocks, XCD-bijective
    const int o0 = (vid & 15) * 128;               // 16 M-tiles
    const int n0 = (vid >> 4) * 256;               // 16 N-tiles

    f32x4 acc[4][4];
#pragma unroll
    for (int i = 0; i < 4; ++i)
#pragma unroll
        for (int j = 0; j < 4; ++j) acc[i][j] = (f32x4){0.f, 0.f, 0.f, 0.f};

    const int swz = (kk & 7) << 3;

#define P5_STAGE_A(st, ks)                                                      \
    {                                                                           \
        ushort* Ad = (ushort*)SMEM + (st) * 8192;                               \
        _Pragma("unroll")                                                       \
        for (int ii = 0; ii < 2; ++ii) {                                        \
            const int idx = ii * 512 + t;                                       \
            gld16(Wbf + (size_t)(o0 + (idx >> 3)) * 2048 + (ks) * 64 +          \
                      (idx & 7) * 8,                                            \
                  Ad + idx * 8);                                                \
        }                                                                       \
    }
#define P5_STAGE_B(st, ks, p)                                                   \
    {                                                                           \
        ushort* Bd = (ushort*)(SMEM + 49152) + (st) * 16384;                    \
        _Pragma("unroll")                                                       \
        for (int jj = (p) * 2; jj < (p) * 2 + 2; ++jj) {                        \
            const int idx = jj * 512 + t;                                       \
            gld16(hidT + (size_t)(n0 + (idx >> 3)) * 2048 + (ks) * 64 +         \
                      (idx & 7) * 8,                                            \
                  Bd + idx * 8);                                                \
        }                                                                       \
    }
#define P5_READ(dcv)                                                            \
    _Pragma("unroll")                                                           \
    for (int ms = 0; ms < 4; ++ms)                                              \
        af[ms] = *(const bf16x8*)&Ab[(wr * 64 + ms * 16 + kk) * 64 +            \
                                     (((dcv) * 32 + g * 8) ^ swz)];             \
    _Pragma("unroll")                                                           \
    for (int ns = 0; ns < 4; ++ns)                                              \
        bfr[ns] = *(const bf16x8*)&Bb[(wc * 64 + ns * 16 + kk) * 64 +           \
                                      (((dcv) * 32 + g * 8) ^ swz)];
#define P5_MFMA()                                                               \
    __builtin_amdgcn_s_setprio(1);                                              \
    _Pragma("unroll")                                                           \
    for (int ms = 0; ms < 4; ++ms)                                              \
        _Pragma("unroll")                                                       \
        for (int ns = 0; ns < 4; ++ns)                                          \
            acc[ms][ns] = __builtin_amdgcn_mfma_f32_16x16x32_bf16(              \
                af[ms], bfr[ns], acc[ms][ns], 0, 0, 0);                         \
    __builtin_amdgcn_s_setprio(0);

    P5_STAGE_A(0, 0); P5_STAGE_B(0, 0, 0); P5_STAGE_B(0, 0, 1);
    P5_STAGE_A(1, 1); P5_STAGE_B(1, 1, 0); P5_STAGE_B(1, 1, 1);
    asm volatile("s_waitcnt vmcnt(6)" ::: "memory");
    __builtin_amdgcn_s_barrier();

    int ct = 0, st2 = 2;
    for (int tt = 0; tt < 32; ++tt) {
        const ushort* Ab = (const ushort*)SMEM + ct * 8192;
        const ushort* Bb = (const ushort*)(SMEM + 49152) + ct * 16384;
        bf16x8 af[4], bfr[4];

        // ---- phase 0 (dc=0): ds_read 8 ∥ stage A + B-half ----
        P5_READ(0);
        if (tt < 30) { P5_STAGE_A(st2, tt + 2); P5_STAGE_B(st2, tt + 2, 0); }
        __builtin_amdgcn_s_barrier();
        asm volatile("s_waitcnt lgkmcnt(0)" ::: "memory");
        P5_MFMA();
        __builtin_amdgcn_s_barrier();

        // ---- phase 1 (dc=1): ds_read 8 ∥ stage B-half; counted vmcnt ----
        P5_READ(1);
        if (tt < 30) P5_STAGE_B(st2, tt + 2, 1);
        if (tt < 30) { asm volatile("s_waitcnt vmcnt(6)" ::: "memory"); }
        else         { asm volatile("s_waitcnt vmcnt(0)" ::: "memory"); }
        __builtin_amdgcn_s_barrier();
        asm volatile("s_waitcnt lgkmcnt(0)" ::: "memory");
        P5_MFMA();
        __builtin_amdgcn_s_barrier();

        ct = (ct == 2) ? 0 : ct + 1;
        st2 = (st2 == 2) ? 0 : st2 + 1;
    }
#undef P5_STAGE_A
#undef P5_STAGE_B
#undef P5_READ
#undef P5_MFMA

#pragma unroll
    for (int ms = 0; ms < 4; ++ms)
#pragma unroll
        for (int ns = 0; ns < 4; ++ns) {
            const int o = o0 + wr * 64 + ms * 16 + g * 4;
            const int n = n0 + wc * 64 + ns * 16 + kk;
            const int bb = n >> 10, qq = n & 1023;
            float* op = out + ((size_t)(bb * Cc + o)) * Ss + qq;
#pragma unroll
            for (int r = 0; r < 4; ++r) op[(size_t)r * Ss] = acc[ms][ns][r];
        }
}

extern "C" void kernel_launch(void* const* d_in, const int* in_sizes, int n_in,
                              void* d_out, int out_size, void* d_ws, size_t ws_size,
                              hipStream_t stream) {
    const float*    keys    = (const float*)d_in[0];
    const float*    values  = (const float*)d_in[1];
    const float*    queries = (const float*)d_in[2];
    const unsigned* mask    = (const unsigned*)d_in[3];
    const float*    w_out   = (const float*)d_in[4];
    float* out = (float*)d_out;

    char* ws = (char*)d_ws;
    float*  bias = (float*)ws;                              // 16 KB
    ushort* Wbf  = (ushort*)(ws + 16384);                   // 8 MB
    ushort* Kt   = (ushort*)(ws + 16384 + (8u << 20));      // 16 MB
    ushort* Qt   = (ushort*)(ws + 16384 + (24u << 20));     // 16 MB
    ushort* Vbf  = (ushort*)(ws + 16384 + (40u << 20));     // 16 MB
    ushort* hidT = (ushort*)(ws + 16384 + (56u << 20));     // 16 MB

    hipLaunchKernelGGL(prep_all2, dim3(8193), dim3(256), 0, stream,
                       w_out, values, keys, queries, mask,
                       Wbf, Vbf, Kt, Qt, bias);
    hipLaunchKernelGGL(attn10, dim3(256), dim3(512), 0, stream,
                       Qt, Kt, Vbf, bias, hidT);
    hipLaunchKernelGGL(proj5, dim3(256), dim3(512), 0, stream,
                       Wbf, hidT, out);
}

// Round 12
// 115.792 us; speedup vs baseline: 1.6819x; 1.0280x over previous
//
#include <hip/hip_runtime.h>

#define Bq 4
#define Cc 2048
#define Ss 1024
#define Hh 16
#define Dd 128

// 1/sqrt(128) * log2(e): softmax runs in exp2 domain, folded into Q at load
#define QSCALE 0.127517429f

typedef __bf16 bf16x8 __attribute__((ext_vector_type(8)));
typedef float  f32x4  __attribute__((ext_vector_type(4)));

__device__ __forceinline__ ushort f2bf(float f) {
    uint u = __float_as_uint(f);
    u += 0x7FFFu + ((u >> 16) & 1u);   // RNE
    return (ushort)(u >> 16);
}
__device__ __forceinline__ uint pack2bf(float a, float b) {
    return (uint)f2bf(a) | ((uint)f2bf(b) << 16);
}
__device__ __forceinline__ void gld16(const void* g, void* l) {
    __builtin_amdgcn_global_load_lds(
        (const __attribute__((address_space(1))) unsigned int*)g,
        (__attribute__((address_space(3))) unsigned int*)l, 16, 0, 0);
}

// ---------------------------------------------------------------------------
// prep_all3: one kernel, four block-ranges (Q is now inlined in attn).
//   [0,2048)     W fp32[2048][2048] -> bf16, intra-128B XOR swizzle (row&7)
//   [2048,6144)  V fp32 -> bf16, k-permuted (swapped-QK P layout) + swizzle
//   [6144,7168)  K transpose [d][S] -> [S][128] bf16, XOR swizzle by k&7
//   [7168]       mask -> bias (0/-1e30), runtime dtype detection
// ---------------------------------------------------------------------------
__global__ __launch_bounds__(256) void prep_all3(const float* __restrict__ w,
                                                 const float* __restrict__ v,
                                                 const float* __restrict__ keys,
                                                 const unsigned* __restrict__ mask,
                                                 ushort* __restrict__ wb,
                                                 ushort* __restrict__ vb,
                                                 ushort* __restrict__ Kt,
                                                 float* __restrict__ bias) {
    __shared__ __align__(16) float T[128][65];
    const int t = threadIdx.x;
    const int blk = blockIdx.x;

    if (blk < 2048) {
        // ---- W convert+swizzle ----
        const size_t e = ((size_t)blk * 256 + t) * 8;
        const int row = (int)(e >> 11), col = (int)(e & 2047);
        const int colS = (col & ~63) | ((col & 63) ^ ((row & 7) << 3));
        float4 v0 = *(const float4*)&w[e];
        float4 v1 = *(const float4*)&w[e + 4];
        uint4 o;
        o.x = pack2bf(v0.x, v0.y); o.y = pack2bf(v0.z, v0.w);
        o.z = pack2bf(v1.x, v1.y); o.w = pack2bf(v1.z, v1.w);
        *(uint4*)&wb[(size_t)row * 2048 + colS] = o;
    } else if (blk < 6144) {
        // ---- V convert + k-permute + swizzle ----
        const int tid = (blk - 2048) * 256 + t;    // 0 .. 1M-1
        const int row = tid >> 7;                   // 0..8191
        const int cp = tid & 127;
        const int blk64 = (cp >> 3) * 64;
        const int j0 = cp & 7;
        const int b5 = j0 >> 2, h = j0 & 3;
        const float* src = v + (size_t)row * 1024 + blk64 + 32 * b5 + 4 * h;
        float4 A = *(const float4*)src;
        float4 B = *(const float4*)(src + 16);
        uint4 o;
        o.x = pack2bf(A.x, A.y); o.y = pack2bf(A.z, A.w);
        o.z = pack2bf(B.x, B.y); o.w = pack2bf(B.z, B.w);
        *(uint4*)&vb[(size_t)row * 1024 + blk64 + ((j0 * 8) ^ ((row & 7) << 3))] = o;
    } else if (blk < 7168) {
        // ---- K transpose+convert+swizzle ----
        const int b2 = blk - 6144;
        const int s0 = (b2 & 15) * 64;
        const int bh = b2 >> 4;
        const float* src = keys + (size_t)bh * 128 * 1024;
#pragma unroll
        for (int p = 0; p < 8; ++p) {
            const int d = p * 16 + (t >> 4);
            float4 v4 = *(const float4*)&src[(size_t)d * 1024 + s0 + (t & 15) * 4];
            T[d][(t & 15) * 4 + 0] = v4.x;
            T[d][(t & 15) * 4 + 1] = v4.y;
            T[d][(t & 15) * 4 + 2] = v4.z;
            T[d][(t & 15) * 4 + 3] = v4.w;
        }
        __syncthreads();
#pragma unroll
        for (int p = 0; p < 4; ++p) {
            const int k = p * 16 + (t >> 4);
            const int x = t & 15;
            uint4 o;
            o.x = pack2bf(T[x * 8 + 0][k], T[x * 8 + 1][k]);
            o.y = pack2bf(T[x * 8 + 2][k], T[x * 8 + 3][k]);
            o.z = pack2bf(T[x * 8 + 4][k], T[x * 8 + 5][k]);
            o.w = pack2bf(T[x * 8 + 6][k], T[x * 8 + 7][k]);
            const size_t rowbyte = ((size_t)bh * 1024 + s0 + k) * 256;
            const int boff = (x * 16) ^ ((k & 7) << 4);
            *(uint4*)((char*)Kt + rowbyte + boff) = o;
        }
    } else {
        // ---- mask -> bias ----
        __shared__ int f01, ff;
        if (t == 0) { f01 = 0; ff = 0; }
        __syncthreads();
        int a = 0, c = 0;
        for (int i = t; i < 1024; i += 256) {
            unsigned vv = mask[i];
            if (vv != 0u && vv != 1u) a = 1;
            if (vv != 0u && vv != 0x3F800000u) c = 1;
        }
        if (a) atomicOr(&f01, 1);
        if (c) atomicOr(&ff, 1);
        __syncthreads();
        const int mode = f01 ? (ff ? 1 : 2) : 0;
        const int* mi = (const int*)mask;
        const unsigned char* mb = (const unsigned char*)mask;
        const float* mf = (const float*)mask;
        for (int i = t; i < Bq * Ss; i += 256) {
            bool on;
            if (mode == 0)      on = (mi[i] != 0);
            else if (mode == 1) on = (mb[i] != 0);
            else                on = (mf[i] != 0.0f);
            bias[i] = on ? 0.0f : -1e30f;
        }
    }
}

// ---------------------------------------------------------------------------
// MFMA flash attention v11. 256 blocks x 512 thr (8 waves); q-tile 256;
// KVBLK 64 triple-buffered, counted vmcnt(4); swapped-QK, P in registers,
// bias as MFMA C-init, half-chunk issue order. NEW: Q fragments built
// in-kernel — coalesced gld16 staging of Q fp32 [64 d][256 q] into SMEM
// (2 passes), per-lane LDS extraction + QSCALE + pack (identical rounding
// to the old prep path). Kills the Qt HBM round-trip.
// ---------------------------------------------------------------------------
__global__ __launch_bounds__(512) void attn11(const float* __restrict__ queries,
                                              const ushort* __restrict__ Kt,
                                              const ushort* __restrict__ Vbf,
                                              const float* __restrict__ bias,
                                              ushort* __restrict__ hidT) {
    __shared__ __align__(16) char SMEM[102400];
    // main loop: K 3x16KB at 0; V 3x16KB at 49152; bias at 98304
    // prologue: Q fp32 stage [64][256] = 64 KB at 0 (freed before K/V staging)
    float* biasS = (float*)(SMEM + 98304);

    const int t = threadIdx.x, l = t & 63, w = t >> 6;   // w = 0..7
    const int kk = l & 15, g = l >> 4;

    const int bid = blockIdx.x;
    const int vid = (bid & 7) * 32 + (bid >> 3);   // XCD-affine (256 blocks)
    const int bh = vid >> 2, qt = vid & 3;
    const int b = bh >> 4, hh = bh & 15;
    const int q0 = qt * 256;
    const size_t bhbase = (size_t)bh * 1024;

    for (int i = t; i < Ss; i += 512) biasS[i] = bias[b * Ss + i];

    // ---- Q prologue: stage [64 d][256 q] fp32, extract fragments ----
    bf16x8 qf[2][4];
    {
        const float* Qg = queries + (size_t)(b * Cc + hh * Dd) * Ss;
        float* Qstg = (float*)SMEM;
#pragma unroll
        for (int half = 0; half < 2; ++half) {
#pragma unroll
            for (int it = 0; it < 8; ++it) {
                const int row = it * 8 + w;         // wave-uniform dest row
                gld16(Qg + (size_t)(half * 64 + row) * 1024 + q0 + l * 4,
                      (char*)Qstg + row * 1024);
            }
            asm volatile("s_waitcnt vmcnt(0)" ::: "memory");
            __builtin_amdgcn_s_barrier();
#pragma unroll
            for (int dch = 0; dch < 2; ++dch) {
                const int dc = half * 2 + dch;
#pragma unroll
                for (int qs = 0; qs < 2; ++qs) {
                    const int q = w * 32 + qs * 16 + kk;
                    float f[8];
#pragma unroll
                    for (int j = 0; j < 8; ++j) {
                        const int dl = dc * 32 + g * 8 + j - half * 64;  // 0..63
                        f[j] = Qstg[dl * 256 + q];
                    }
                    uint4 u;
                    u.x = pack2bf(f[0] * QSCALE, f[1] * QSCALE);
                    u.y = pack2bf(f[2] * QSCALE, f[3] * QSCALE);
                    u.z = pack2bf(f[4] * QSCALE, f[5] * QSCALE);
                    u.w = pack2bf(f[6] * QSCALE, f[7] * QSCALE);
                    qf[qs][dc] = *(bf16x8*)&u;
                }
            }
            __builtin_amdgcn_s_barrier();   // extraction done before overwrite
        }
    }

    float lrun[2] = {0.0f, 0.0f};
    f32x4 hacc[2][8];
#pragma unroll
    for (int qs = 0; qs < 2; ++qs)
#pragma unroll
        for (int i = 0; i < 8; ++i) hacc[qs][i] = (f32x4){0.f, 0.f, 0.f, 0.f};

#define ATTN_STAGE(bufi, cki)                                                   \
    {                                                                           \
        const int k0n = (cki) * 64;                                             \
        ushort* Kd = (ushort*)SMEM + (bufi) * 8192;                             \
        ushort* Vd = (ushort*)(SMEM + 49152) + (bufi) * 8192;                   \
        _Pragma("unroll")                                                       \
        for (int ii = 0; ii < 4; ++ii) {                                        \
            const int inst = ii * 8 + w;                                        \
            if (inst < 16) {                                                    \
                gld16(Kt + (bhbase + k0n + inst * 4 + (l >> 4)) * 128 +         \
                          (l & 15) * 8,                                         \
                      Kd + inst * 512);                                         \
            } else {                                                            \
                const int i2 = inst - 16;                                       \
                gld16(Vbf + ((size_t)bh * 128 + i2 * 8 + (l >> 3)) * 1024 +     \
                          k0n + (l & 7) * 8,                                    \
                      Vd + i2 * 512);                                           \
            }                                                                   \
        }                                                                       \
    }

#define QK_HALF(h)                                                               \
    _Pragma("unroll")                                                            \
    for (int n2 = 0; n2 < 2; ++n2) {                                             \
        const int ns = 2 * (h) + n2;                                             \
        const f32x4 ci = *(const f32x4*)&biasS[k0 + ns * 16 + g * 4];            \
        bf16x8 kf[4];                                                            \
        const ushort* kr = KTb + (ns * 16 + kk) * 128;                           \
        _Pragma("unroll")                                                        \
        for (int dc = 0; dc < 4; ++dc)                                           \
            kf[dc] = *(const bf16x8*)(kr + ((dc * 32 + g * 8) ^ ((kk & 7) << 3)));\
        _Pragma("unroll")                                                        \
        for (int qs = 0; qs < 2; ++qs) {                                         \
            f32x4 a = ci;                                                        \
            _Pragma("unroll")                                                    \
            for (int dc = 0; dc < 4; ++dc)                                       \
                a = __builtin_amdgcn_mfma_f32_16x16x32_bf16(                     \
                    kf[dc], qf[qs][dc], a, 0, 0, 0);                             \
            sc[qs][ns] = a;                                                      \
        }                                                                        \
    }

#define SM_HALF(h)                                                               \
    _Pragma("unroll")                                                            \
    for (int qs = 0; qs < 2; ++qs) {                                             \
        float pv0[4], pv1[4];                                                    \
        _Pragma("unroll")                                                        \
        for (int r = 0; r < 4; ++r) {                                            \
            pv0[r] = exp2f(sc[qs][2 * (h)][r]);                                  \
            pv1[r] = exp2f(sc[qs][2 * (h) + 1][r]);                              \
        }                                                                        \
        lrun[qs] += (pv0[0] + pv0[1] + pv0[2] + pv0[3])                          \
                  + (pv1[0] + pv1[1] + pv1[2] + pv1[3]);                         \
        bf16x8 vpk;                                                              \
        _Pragma("unroll")                                                        \
        for (int j = 0; j < 4; ++j) { vpk[j] = (__bf16)pv0[j];                   \
                                      vpk[j + 4] = (__bf16)pv1[j]; }             \
        pb[qs][h] = vpk;                                                         \
    }

#define PV_HALF(h)                                                               \
    _Pragma("unroll")                                                            \
    for (int ds = 0; ds < 8; ++ds) {                                             \
        bf16x8 vf = *(const bf16x8*)(Vsb + (ds * 16 + kk) * 64 +                 \
                        (((h) * 32 + g * 8) ^ ((kk & 7) << 3)));                 \
        hacc[0][ds] = __builtin_amdgcn_mfma_f32_16x16x32_bf16(                   \
            vf, pb[0][h], hacc[0][ds], 0, 0, 0);                                 \
        hacc[1][ds] = __builtin_amdgcn_mfma_f32_16x16x32_bf16(                   \
            vf, pb[1][h], hacc[1][ds], 0, 0, 0);                                 \
    }

#define ATTN_COMPUTE(bi, ck)                                                     \
    {                                                                            \
        const int k0 = (ck) * 64;                                                \
        const ushort* KTb = (const ushort*)SMEM + (bi) * 8192;                   \
        const ushort* Vsb = (const ushort*)(SMEM + 49152) + (bi) * 8192;         \
        f32x4 sc[2][4];                                                          \
        bf16x8 pb[2][2];                                                         \
        QK_HALF(0);                                                              \
        QK_HALF(1);                                                              \
        SM_HALF(0);                                                              \
        PV_HALF(0);                                                              \
        SM_HALF(1);                                                              \
        PV_HALF(1);                                                              \
    }

    // prologue: 2 tiles in flight; wait for tile 0 only (counted)
    ATTN_STAGE(0, 0);
    ATTN_STAGE(1, 1);
    asm volatile("s_waitcnt vmcnt(4)" ::: "memory");
    __builtin_amdgcn_s_barrier();

    int cb = 0, sb = 2;
    for (int ck = 0; ck < 14; ++ck) {
        ATTN_STAGE(sb, ck + 2);
        ATTN_COMPUTE(cb, ck);
        asm volatile("s_waitcnt vmcnt(4)" ::: "memory");  // next tile landed
        __builtin_amdgcn_s_barrier();
        cb = (cb == 2) ? 0 : cb + 1;
        sb = (sb == 2) ? 0 : sb + 1;
    }
    ATTN_COMPUTE(cb, 14);
    asm volatile("s_waitcnt vmcnt(0)" ::: "memory");
    __builtin_amdgcn_s_barrier();
    cb = (cb == 2) ? 0 : cb + 1;
    ATTN_COMPUTE(cb, 15);
#undef ATTN_STAGE
#undef ATTN_COMPUTE
#undef QK_HALF
#undef SM_HALF
#undef PV_HALF

    float linv[2];
#pragma unroll
    for (int qs = 0; qs < 2; ++qs) {
        float s = lrun[qs];
        s += __shfl_xor(s, 16);
        s += __shfl_xor(s, 32);
        linv[qs] = 1.0f / s;
    }

    __syncthreads();   // done with K/V buffers; reuse as [256 q][128 d] stage
    {
        ushort* hs = (ushort*)SMEM;
#pragma unroll
        for (int qs = 0; qs < 2; ++qs) {
            const int row = w * 32 + qs * 16 + kk;
#pragma unroll
            for (int ds = 0; ds < 8; ++ds) {
                uint2 pk;
                pk.x = pack2bf(hacc[qs][ds][0] * linv[qs], hacc[qs][ds][1] * linv[qs]);
                pk.y = pack2bf(hacc[qs][ds][2] * linv[qs], hacc[qs][ds][3] * linv[qs]);
                const int off = row * 256 + ((ds * 32 + g * 8) ^ ((row & 7) << 4));
                *(uint2*)((char*)hs + off) = pk;
            }
        }
    }
    __syncthreads();

    const char* hsb = (const char*)SMEM;
#pragma unroll
    for (int it = 0; it < 8; ++it) {
        const int idx = it * 512 + t;                  // 0..4095
        const int q = idx >> 4, x = idx & 15;
        uint4 vv = *(const uint4*)(hsb + q * 256 + x * 16);
        *(uint4*)((char*)hidT + ((size_t)(b * Ss + q0 + q)) * 4096 + hh * 256 + x * 16) = vv;
    }
}

// ---------------------------------------------------------------------------
// proj5: out[2048][4096] = W @ hidT^T. BM=128, BN=256, BK=64, 512 thr
// (8 waves 2Mx4N, per-wave 64x64). 2 phases per K-tile, 16 MFMA/phase,
// ds_read ∥ stage-issue ∥ MFMA per phase, 3-buffer LDS, vmcnt(6)/K-tile.
// ---------------------------------------------------------------------------
__global__ __launch_bounds__(512, 2) void proj5(const ushort* __restrict__ Wbf,
                                                const ushort* __restrict__ hidT,
                                                float* __restrict__ out) {
    __shared__ __align__(16) char SMEM[147456];
    const int t = threadIdx.x, l = t & 63, w = t >> 6;
    const int kk = l & 15, g = l >> 4;
    const int wr = w >> 2, wc = w & 3;

    const int bid = blockIdx.x;
    const int vid = (bid & 7) * 32 + (bid >> 3);   // 256 blocks, XCD-bijective
    const int o0 = (vid & 15) * 128;               // 16 M-tiles
    const int n0 = (vid >> 4) * 256;               // 16 N-tiles

    f32x4 acc[4][4];
#pragma unroll
    for (int i = 0; i < 4; ++i)
#pragma unroll
        for (int j = 0; j < 4; ++j) acc[i][j] = (f32x4){0.f, 0.f, 0.f, 0.f};

    const int swz = (kk & 7) << 3;

#define P5_STAGE_A(st, ks)                                                      \
    {                                                                           \
        ushort* Ad = (ushort*)SMEM + (st) * 8192;                               \
        _Pragma("unroll")                                                       \
        for (int ii = 0; ii < 2; ++ii) {                                        \
            const int idx = ii * 512 + t;                                       \
            gld16(Wbf + (size_t)(o0 + (idx >> 3)) * 2048 + (ks) * 64 +          \
                      (idx & 7) * 8,                                            \
                  Ad + idx * 8);                                                \
        }                                                                       \
    }
#define P5_STAGE_B(st, ks, p)                                                   \
    {                                                                           \
        ushort* Bd = (ushort*)(SMEM + 49152) + (st) * 16384;                    \
        _Pragma("unroll")                                                       \
        for (int jj = (p) * 2; jj < (p) * 2 + 2; ++jj) {                        \
            const int idx = jj * 512 + t;                                       \
            gld16(hidT + (size_t)(n0 + (idx >> 3)) * 2048 + (ks) * 64 +         \
                      (idx & 7) * 8,                                            \
                  Bd + idx * 8);                                                \
        }                                                                       \
    }
#define P5_READ(dcv)                                                            \
    _Pragma("unroll")                                                           \
    for (int ms = 0; ms < 4; ++ms)                                              \
        af[ms] = *(const bf16x8*)&Ab[(wr * 64 + ms * 16 + kk) * 64 +            \
                                     (((dcv) * 32 + g * 8) ^ swz)];             \
    _Pragma("unroll")                                                           \
    for (int ns = 0; ns < 4; ++ns)                                              \
        bfr[ns] = *(const bf16x8*)&Bb[(wc * 64 + ns * 16 + kk) * 64 +           \
                                      (((dcv) * 32 + g * 8) ^ swz)];
#define P5_MFMA()                                                               \
    __builtin_amdgcn_s_setprio(1);                                              \
    _Pragma("unroll")                                                           \
    for (int ms = 0; ms < 4; ++ms)                                              \
        _Pragma("unroll")                                                       \
        for (int ns = 0; ns < 4; ++ns)                                          \
            acc[ms][ns] = __builtin_amdgcn_mfma_f32_16x16x32_bf16(              \
                af[ms], bfr[ns], acc[ms][ns], 0, 0, 0);                         \
    __builtin_amdgcn_s_setprio(0);

    P5_STAGE_A(0, 0); P5_STAGE_B(0, 0, 0); P5_STAGE_B(0, 0, 1);
    P5_STAGE_A(1, 1); P5_STAGE_B(1, 1, 0); P5_STAGE_B(1, 1, 1);
    asm volatile("s_waitcnt vmcnt(6)" ::: "memory");
    __builtin_amdgcn_s_barrier();

    int ct = 0, st2 = 2;
    for (int tt = 0; tt < 32; ++tt) {
        const ushort* Ab = (const ushort*)SMEM + ct * 8192;
        const ushort* Bb = (const ushort*)(SMEM + 49152) + ct * 16384;
        bf16x8 af[4], bfr[4];

        // ---- phase 0 (dc=0): ds_read 8 ∥ stage A + B-half ----
        P5_READ(0);
        if (tt < 30) { P5_STAGE_A(st2, tt + 2); P5_STAGE_B(st2, tt + 2, 0); }
        __builtin_amdgcn_s_barrier();
        asm volatile("s_waitcnt lgkmcnt(0)" ::: "memory");
        P5_MFMA();
        __builtin_amdgcn_s_barrier();

        // ---- phase 1 (dc=1): ds_read 8 ∥ stage B-half; counted vmcnt ----
        P5_READ(1);
        if (tt < 30) P5_STAGE_B(st2, tt + 2, 1);
        if (tt < 30) { asm volatile("s_waitcnt vmcnt(6)" ::: "memory"); }
        else         { asm volatile("s_waitcnt vmcnt(0)" ::: "memory"); }
        __builtin_amdgcn_s_barrier();
        asm volatile("s_waitcnt lgkmcnt(0)" ::: "memory");
        P5_MFMA();
        __builtin_amdgcn_s_barrier();

        ct = (ct == 2) ? 0 : ct + 1;
        st2 = (st2 == 2) ? 0 : st2 + 1;
    }
#undef P5_STAGE_A
#undef P5_STAGE_B
#undef P5_READ
#undef P5_MFMA

#pragma unroll
    for (int ms = 0; ms < 4; ++ms)
#pragma unroll
        for (int ns = 0; ns < 4; ++ns) {
            const int o = o0 + wr * 64 + ms * 16 + g * 4;
            const int n = n0 + wc * 64 + ns * 16 + kk;
            const int bb = n >> 10, qq = n & 1023;
            float* op = out + ((size_t)(bb * Cc + o)) * Ss + qq;
#pragma unroll
            for (int r = 0; r < 4; ++r) op[(size_t)r * Ss] = acc[ms][ns][r];
        }
}

extern "C" void kernel_launch(void* const* d_in, const int* in_sizes, int n_in,
                              void* d_out, int out_size, void* d_ws, size_t ws_size,
                              hipStream_t stream) {
    const float*    keys    = (const float*)d_in[0];
    const float*    values  = (const float*)d_in[1];
    const float*    queries = (const float*)d_in[2];
    const unsigned* mask    = (const unsigned*)d_in[3];
    const float*    w_out   = (const float*)d_in[4];
    float* out = (float*)d_out;

    char* ws = (char*)d_ws;
    float*  bias = (float*)ws;                              // 16 KB
    ushort* Wbf  = (ushort*)(ws + 16384);                   // 8 MB
    ushort* Kt   = (ushort*)(ws + 16384 + (8u << 20));      // 16 MB
    ushort* Vbf  = (ushort*)(ws + 16384 + (24u << 20));     // 16 MB
    ushort* hidT = (ushort*)(ws + 16384 + (40u << 20));     // 16 MB

    hipLaunchKernelGGL(prep_all3, dim3(7169), dim3(256), 0, stream,
                       w_out, values, keys, mask, Wbf, Vbf, Kt, bias);
    hipLaunchKernelGGL(attn11, dim3(256), dim3(512), 0, stream,
                       queries, Kt, Vbf, bias, hidT);
    hipLaunchKernelGGL(proj5, dim3(256), dim3(512), 0, stream,
                       Wbf, hidT, out);
}